// Round 2
// baseline (163.690 us; speedup 1.0000x reference)
//
#include <hip/hip_runtime.h>
#include <hip/hip_bf16.h>
#include <math.h>

#define H 512
#define B 64
#define L 4096

// ---------------------------------------------------------------------------
// Kernel 1: v[b,h] = sum_o hidden[b,o] * W[o,h];  c[b] = sum_o hidden[b,o]*bias[o]
// 64 blocks (one per b), 512 threads (one per h).
// ---------------------------------------------------------------------------
__global__ __launch_bounds__(512) void proj_kernel(
    const float* __restrict__ hidden,   // [B,H]
    const float* __restrict__ W,        // [H,H]  (o-major: W[o*H+h])
    const float* __restrict__ bias,     // [H]
    float* __restrict__ v,              // [B,H]
    float* __restrict__ c)              // [B]
{
    const int b = blockIdx.x;
    const int h = threadIdx.x;

    __shared__ float hsh[H];
    hsh[h] = hidden[b * H + h];
    __syncthreads();

    float acc = 0.f;
#pragma unroll 8
    for (int o = 0; o < H; ++o) {
        acc = fmaf(hsh[o], W[o * H + h], acc);
    }
    v[b * H + h] = acc;

    // c[b] = dot(hidden[b,:], bias)
    float p = hsh[h] * bias[h];
#pragma unroll
    for (int off = 32; off; off >>= 1) p += __shfl_xor(p, off);

    __shared__ float red[8];
    if ((h & 63) == 0) red[h >> 6] = p;
    __syncthreads();
    if (h == 0) {
        float s = 0.f;
#pragma unroll
        for (int i = 0; i < 8; ++i) s += red[i];
        c[b] = s;
    }
}

// ---------------------------------------------------------------------------
// Kernel 2: energies[b,l] = enc[l,b,:] . v[b,:] + c[b]
// Block = one l (4096 blocks, 256 thr = 4 waves). Block reads enc[l,:,:] =
// 128 KB fully contiguous; consecutive blocks read consecutive slabs ->
// sequential HBM sweep. Wave w handles b in [w*16, w*16+16), 4 rows at a
// time via 16-lane groups (reduce = 4 shfl_xor steps). v fragments come
// from L1/L2 (v = 128 KB, resident per-XCD).
// ---------------------------------------------------------------------------
__global__ __launch_bounds__(256) void energies_kernel(
    const float* __restrict__ enc,      // [L,B,H]
    const float* __restrict__ v,        // [B,H]
    const float* __restrict__ c,        // [B]
    float* __restrict__ energies)       // [B,L]
{
    const int l    = blockIdx.x;
    const int wave = threadIdx.x >> 6;
    const int lane = threadIdx.x & 63;
    const int sub  = lane & 15;         // float4 slot within the row
    const int grp  = lane >> 4;         // 0..3: which row of the 4-row pack

    const float4* slab = reinterpret_cast<const float4*>(enc + (size_t)l * B * H);
    const float4* vall = reinterpret_cast<const float4*>(v);

#pragma unroll 2
    for (int it = 0; it < 4; ++it) {
        const int b = wave * 16 + it * 4 + grp;
        const float4* row = slab + (size_t)b * (H / 4);
        const float4* vr  = vall + (size_t)b * (H / 4);

        float s = 0.f;
#pragma unroll
        for (int k = 0; k < 8; ++k) {
            const float4 e = row[k * 16 + sub];
            const float4 w = vr [k * 16 + sub];
            s = fmaf(e.x, w.x, s);
            s = fmaf(e.y, w.y, s);
            s = fmaf(e.z, w.z, s);
            s = fmaf(e.w, w.w, s);
        }
        // reduce across the 16-lane group
        s += __shfl_xor(s, 1);
        s += __shfl_xor(s, 2);
        s += __shfl_xor(s, 4);
        s += __shfl_xor(s, 8);

        if (sub == 0) energies[(size_t)b * L + l] = s + c[b];
    }
}

// ---------------------------------------------------------------------------
// Kernel 3: out[b,0,:] = softmax(energies[b,:])
// 64 blocks (one per b), 256 threads, 16 elements/thread in registers.
// ---------------------------------------------------------------------------
__global__ __launch_bounds__(256) void softmax_kernel(
    const float* __restrict__ energies, // [B,L]
    float* __restrict__ out)            // [B,1,L]
{
    const int b = blockIdx.x;
    const int t = threadIdx.x;
    const float* e = energies + (size_t)b * L;
    float* o = out + (size_t)b * L;

    float vals[16];
    float m = -1e30f;
#pragma unroll
    for (int i = 0; i < 16; ++i) {
        vals[i] = e[t + i * 256];
        m = fmaxf(m, vals[i]);
    }
#pragma unroll
    for (int off = 32; off; off >>= 1) m = fmaxf(m, __shfl_xor(m, off));

    __shared__ float redm[4];
    if ((t & 63) == 0) redm[t >> 6] = m;
    __syncthreads();
    m = fmaxf(fmaxf(redm[0], redm[1]), fmaxf(redm[2], redm[3]));

    float s = 0.f;
#pragma unroll
    for (int i = 0; i < 16; ++i) {
        vals[i] = expf(vals[i] - m);
        s += vals[i];
    }
#pragma unroll
    for (int off = 32; off; off >>= 1) s += __shfl_xor(s, off);

    __shared__ float reds[4];
    if ((t & 63) == 0) reds[t >> 6] = s;
    __syncthreads();
    s = reds[0] + reds[1] + reds[2] + reds[3];

    const float inv = 1.0f / s;
#pragma unroll
    for (int i = 0; i < 16; ++i) o[t + i * 256] = vals[i] * inv;
}

// ---------------------------------------------------------------------------
extern "C" void kernel_launch(void* const* d_in, const int* in_sizes, int n_in,
                              void* d_out, int out_size, void* d_ws, size_t ws_size,
                              hipStream_t stream)
{
    const float* hidden = (const float*)d_in[0];   // [1,B,H]
    const float* enc    = (const float*)d_in[1];   // [L,B,H]
    const float* W      = (const float*)d_in[2];   // [H,H]
    const float* bias   = (const float*)d_in[3];   // [H]
    float* out = (float*)d_out;                    // [B,1,L]

    float* v        = (float*)d_ws;                // B*H   = 32768 floats
    float* c        = v + (size_t)B * H;           // B     = 64 floats
    float* energies = c + B;                       // B*L   = 262144 floats

    proj_kernel<<<B, H, 0, stream>>>(hidden, W, bias, v, c);

    energies_kernel<<<L, 256, 0, stream>>>(enc, v, c, energies);

    softmax_kernel<<<B, 256, 0, stream>>>(energies, out);
}

// Round 3
// 145.020 us; speedup vs baseline: 1.1287x; 1.1287x over previous
//
#include <hip/hip_runtime.h>
#include <hip/hip_bf16.h>
#include <math.h>

#define H 512
#define B 64
#define L 4096

// ---------------------------------------------------------------------------
// Kernel 1: v[b,h] = sum_o hidden[b,o] * W[o,h];  c[b] = sum_o hidden[b,o]*bias[o]
// 64 blocks (one per b), 512 threads (one per h).
// ---------------------------------------------------------------------------
__global__ __launch_bounds__(512) void proj_kernel(
    const float* __restrict__ hidden,   // [B,H]
    const float* __restrict__ W,        // [H,H]  (o-major: W[o*H+h])
    const float* __restrict__ bias,     // [H]
    float* __restrict__ v,              // [B,H]
    float* __restrict__ c)              // [B]
{
    const int b = blockIdx.x;
    const int h = threadIdx.x;

    __shared__ float hsh[H];
    hsh[h] = hidden[b * H + h];
    __syncthreads();

    float acc = 0.f;
#pragma unroll 8
    for (int o = 0; o < H; ++o) {
        acc = fmaf(hsh[o], W[o * H + h], acc);
    }
    v[b * H + h] = acc;

    // c[b] = dot(hidden[b,:], bias)
    float p = hsh[h] * bias[h];
#pragma unroll
    for (int off = 32; off; off >>= 1) p += __shfl_xor(p, off);

    __shared__ float red[8];
    if ((h & 63) == 0) red[h >> 6] = p;
    __syncthreads();
    if (h == 0) {
        float s = 0.f;
#pragma unroll
        for (int i = 0; i < 8; ++i) s += red[i];
        c[b] = s;
    }
}

// ---------------------------------------------------------------------------
// Kernel 2: energies[b,l] = enc[l,b,:] . v[b,:] + c[b]
//
// Wave owns 4 CONSECUTIVE b's (v fragments in 32 VGPRs, loaded once).
// Per l, the wave reads an 8 KB fully-contiguous chunk (4 rows x 2 KB,
// consecutive b's are contiguous in [L,B,H]) as 8 back-to-back 1 KB
// wave-loads. Block = 4 waves = 16 consecutive b's = 32 KB contiguous per l.
// Grid = (B/16) x (L/16) = 1024 blocks; each wave handles 16 l's.
// ---------------------------------------------------------------------------
#define BG 4        // b's per wave
#define BPB 16      // b's per block
#define NL 16       // l's per wave

__global__ __launch_bounds__(256) void energies_kernel(
    const float* __restrict__ enc,      // [L,B,H]
    const float* __restrict__ v,        // [B,H]
    const float* __restrict__ c,        // [B]
    float* __restrict__ energies)       // [B,L]
{
    const int wave = threadIdx.x >> 6;
    const int lane = threadIdx.x & 63;

    const int nbg    = B / BPB;              // 4
    const int bgrp   = blockIdx.x % nbg;
    const int lchunk = blockIdx.x / nbg;
    const int l0     = lchunk * NL;
    const int b0     = bgrp * BPB + wave * BG;   // this wave's first b

    // v fragments for 4 b's: row b = float4 indices [b*128, (b+1)*128)
    const float4* v4 = reinterpret_cast<const float4*>(v);
    float4 vf0[BG], vf1[BG];
    float  cb[BG];
#pragma unroll
    for (int r = 0; r < BG; ++r) {
        vf0[r] = v4[(size_t)(b0 + r) * 128 + lane];
        vf1[r] = v4[(size_t)(b0 + r) * 128 + 64 + lane];
        cb[r]  = c[b0 + r];
    }

#pragma unroll 2
    for (int i = 0; i < NL; ++i) {
        const int l = l0 + i;
        // 8 KB contiguous: rows (l, b0..b0+3)
        const float4* chunk =
            reinterpret_cast<const float4*>(enc + ((size_t)l * B + b0) * H);

        float4 e[8];
#pragma unroll
        for (int k = 0; k < 8; ++k) e[k] = chunk[k * 64 + lane];

        float s[BG];
#pragma unroll
        for (int r = 0; r < BG; ++r) {
            const float4 ea = e[2 * r];
            const float4 eb = e[2 * r + 1];
            float t = ea.x * vf0[r].x + ea.y * vf0[r].y
                    + ea.z * vf0[r].z + ea.w * vf0[r].w;
            t = fmaf(eb.x, vf1[r].x, t);
            t = fmaf(eb.y, vf1[r].y, t);
            t = fmaf(eb.z, vf1[r].z, t);
            t = fmaf(eb.w, vf1[r].w, t);
            s[r] = t;
        }

        // 4 independent full-wave reduces (chains interleave)
#pragma unroll
        for (int off = 32; off; off >>= 1) {
#pragma unroll
            for (int r = 0; r < BG; ++r) s[r] += __shfl_xor(s[r], off);
        }

        if (lane == 0) {
#pragma unroll
            for (int r = 0; r < BG; ++r)
                energies[(size_t)(b0 + r) * L + l] = s[r] + cb[r];
        }
    }
}

// ---------------------------------------------------------------------------
// Kernel 3: out[b,0,:] = softmax(energies[b,:])
// 64 blocks (one per b), 256 threads, 16 elements/thread in registers.
// ---------------------------------------------------------------------------
__global__ __launch_bounds__(256) void softmax_kernel(
    const float* __restrict__ energies, // [B,L]
    float* __restrict__ out)            // [B,1,L]
{
    const int b = blockIdx.x;
    const int t = threadIdx.x;
    const float* e = energies + (size_t)b * L;
    float* o = out + (size_t)b * L;

    float vals[16];
    float m = -1e30f;
#pragma unroll
    for (int i = 0; i < 16; ++i) {
        vals[i] = e[t + i * 256];
        m = fmaxf(m, vals[i]);
    }
#pragma unroll
    for (int off = 32; off; off >>= 1) m = fmaxf(m, __shfl_xor(m, off));

    __shared__ float redm[4];
    if ((t & 63) == 0) redm[t >> 6] = m;
    __syncthreads();
    m = fmaxf(fmaxf(redm[0], redm[1]), fmaxf(redm[2], redm[3]));

    float s = 0.f;
#pragma unroll
    for (int i = 0; i < 16; ++i) {
        vals[i] = expf(vals[i] - m);
        s += vals[i];
    }
#pragma unroll
    for (int off = 32; off; off >>= 1) s += __shfl_xor(s, off);

    __shared__ float reds[4];
    if ((t & 63) == 0) reds[t >> 6] = s;
    __syncthreads();
    s = reds[0] + reds[1] + reds[2] + reds[3];

    const float inv = 1.0f / s;
#pragma unroll
    for (int i = 0; i < 16; ++i) o[t + i * 256] = vals[i] * inv;
}

// ---------------------------------------------------------------------------
extern "C" void kernel_launch(void* const* d_in, const int* in_sizes, int n_in,
                              void* d_out, int out_size, void* d_ws, size_t ws_size,
                              hipStream_t stream)
{
    const float* hidden = (const float*)d_in[0];   // [1,B,H]
    const float* enc    = (const float*)d_in[1];   // [L,B,H]
    const float* W      = (const float*)d_in[2];   // [H,H]
    const float* bias   = (const float*)d_in[3];   // [H]
    float* out = (float*)d_out;                    // [B,1,L]

    float* v        = (float*)d_ws;                // B*H   = 32768 floats
    float* c        = v + (size_t)B * H;           // B     = 64 floats
    float* energies = c + B;                       // B*L   = 262144 floats

    proj_kernel<<<B, H, 0, stream>>>(hidden, W, bias, v, c);

    const int nblocks = (B / BPB) * (L / NL);      // 4 * 256 = 1024
    energies_kernel<<<nblocks, 256, 0, stream>>>(enc, v, c, energies);

    softmax_kernel<<<B, 256, 0, stream>>>(energies, out);
}